// Round 1
// 483.353 us; speedup vs baseline: 1.0057x; 1.0057x over previous
//
#include <hip/hip_runtime.h>
#include <cmath>

// ---------------------------------------------------------------------------
// SpatialLinearAttention — bf16 MFMA GEMMs + fused softmax/context chain.
//   x:(2,256,16,64,64) f32, w_qkv:(768,256) f32, w_out:(256,256) f32, b_out:(256,)
// Per chunk of CF frames (j = fl*4096 + n):
//   C0: xbf_t[j][c] = bf16(x^T)                      (k-contiguous)
//   C1: wq_bf = bf16(w_qkv)                          (once)
//   K1: qkv_t[j][o] = MFMA(wq[o][c], xbf[j][c]); q tiles (o<256) get the
//       d-softmax (*1/sqrt(32)) fused in the epilogue.  k,v stored raw bf16.
//   S1: k_kstat1: per (fl, j-split): online (m,s) partials per k-col (256)
//   S2: k_kstat2: combine 16 partials -> (M, 1/S) per (fl, k-col)
//   CX: k_ctx: per (fl, j-split): P[h][d][e] += exp(k[d,j]-M_d) * v[e,j]
//   W2: k_w2fold: C = invS_d * sum_js P; W2[o][h*32+d] = sum_e w_out[o][..e]*C[d][e]
//   K5: out = MFMA(q[j][c2], W2[o][c2]) + b_out, fp32 direct store
//
// R1 changes (vs 486us baseline):
//   - LDS XOR swizzle (slot ^= (row>>1)&3, 16B units) on both MFMA kernels'
//     [128][32] bf16 tiles. Applied as pre-swizzled GLOBAL source (rule #21:
//     global_load_lds dest must stay linear) + same XOR on fragment ds_read.
//     Kills the 8-way bank conflict (8.39M conflict cycles measured).
//   - Grid transposed: o-tiles on blockIdx.x (fast-varying), j-tiles on y.
//     All o-blocks of a j-tile run adjacently -> xbf/q fetched once from HBM
//     (FETCH was 200MB vs 68MB intrinsic: LLC evicted by streaming writes).
// ---------------------------------------------------------------------------

typedef unsigned short u16;
typedef __attribute__((ext_vector_type(4))) unsigned short u16x4;
typedef __attribute__((ext_vector_type(8))) unsigned short u16x8;
typedef __attribute__((ext_vector_type(4))) unsigned int   u32x4;
typedef __attribute__((ext_vector_type(8))) short bf16x8;
typedef __attribute__((ext_vector_type(4))) float f32x4;

#define XCH_STRIDE 65536    // x stride over c: 16*4096
#define XB_STRIDE  16777216 // x stride over b: 256*16*4096

__device__ __forceinline__ float bf2f(u16 u) {
    union { unsigned int i; float f; } w; w.i = ((unsigned int)u) << 16; return w.f;
}
__device__ __forceinline__ u16 f2bf(float f) {
    union { float f; unsigned int i; } w; w.f = f;
    return (u16)((w.i + 0x7FFFu + ((w.i >> 16) & 1u)) >> 16);
}
__device__ __forceinline__ void async16(const void* g, void* l) {
    __builtin_amdgcn_global_load_lds(
        (const __attribute__((address_space(1))) unsigned int*)g,
        (__attribute__((address_space(3))) unsigned int*)l, 16, 0, 0);
}

// ---------------- C0: x (b,c,f,n) f32 -> xbf_t[(fl,n)][c] bf16 --------------
__global__ __launch_bounds__(256) void k_cvt_x(const float* __restrict__ x,
                                               u16* __restrict__ xbf, int fr0)
{
    const int tid = threadIdx.x;
    const int n0 = blockIdx.x * 64;
    const int c0 = blockIdx.y * 64;
    const int fl = blockIdx.z;
    const int frame = fr0 + fl, b = frame >> 4, f = frame & 15;
    const float* xb = x + (size_t)b * XB_STRIDE + (size_t)f * 4096;
    __shared__ float T[64][65];
    const int nn = tid & 63, cq = tid >> 6;
    #pragma unroll
    for (int r = 0; r < 16; ++r) {
        const int cl = r * 4 + cq;
        T[cl][nn] = xb[(size_t)(c0 + cl) * XCH_STRIDE + n0 + nn];
    }
    __syncthreads();
    const int jl = tid >> 2, c16 = (tid & 3) * 16;
    u16* dst = xbf + ((size_t)fl * 4096 + n0 + jl) * 256 + c0 + c16;
    u16x8 a, bv;
    #pragma unroll
    for (int i = 0; i < 8; ++i) a[i] = f2bf(T[c16 + i][jl]);
    #pragma unroll
    for (int i = 0; i < 8; ++i) bv[i] = f2bf(T[c16 + 8 + i][jl]);
    *(u16x8*)dst = a;
    *(u16x8*)(dst + 8) = bv;
}

// ---------------- C1: w_qkv f32 -> bf16 -------------------------------------
__global__ __launch_bounds__(256) void k_cvt_w(const float* __restrict__ w,
                                               u16* __restrict__ wbf)
{
    const int i = (blockIdx.x * 256 + threadIdx.x) * 8;
    u16x8 o;
    #pragma unroll
    for (int j = 0; j < 8; ++j) o[j] = f2bf(w[i + j]);
    *(u16x8*)(wbf + i) = o;
}

// ---------------- K1: qkv_t[j][o] MFMA, q-softmax fused in epilogue ---------
// grid: (o-tiles=6, j-tiles=CF*32)  — o fast-varying for xbf L2/LLC reuse
__global__ __launch_bounds__(256) void k_qkv_mfma(const u16* __restrict__ xbf,
                                                  const u16* __restrict__ wq,
                                                  u16* __restrict__ qkv)
{
    const int tid = threadIdx.x;
    const int lane = tid & 63, wave = tid >> 6;
    const int ln = lane & 15, quad = lane >> 4;
    const int wm = wave & 1, wn = wave >> 1;
    const int j0 = blockIdx.y * 128;   // N tile (x rows)
    const int o0 = blockIdx.x * 128;   // M tile (wq rows)

    __shared__ __align__(16) u16 sm[128 * 136];  // staging + out-tile overlaid
    u16* As = sm;             // [128 o][32 k]   (16B slots XOR-swizzled)
    u16* Bs = sm + 4096;      // [128 j][32 k]

    f32x4 acc[4][4] = {};
    const int lrow = lane >> 2;
    // pre-swizzled global source: LDS slot (r, c) must hold chunk c^((r>>1)&3)
    const int lk8 = ((lane & 3) ^ ((lrow >> 1) & 3)) * 8;
    // fragment-read swizzle: same XOR; (row>>1)&3 == (ln>>1)&3 (row = 16m+ln)
    const int sw8 = (quad ^ ((ln >> 1) & 3)) * 8;

    for (int kk = 0; kk < 256; kk += 32) {
        __syncthreads();
        #pragma unroll
        for (int p = 0; p < 2; ++p) {
            const int chunk = wave * 2 + p;
            const int r = chunk * 16 + lrow;
            async16(wq  + (size_t)(o0 + r) * 256 + kk + lk8, As + chunk * 512);
            async16(xbf + (size_t)(j0 + r) * 256 + kk + lk8, Bs + chunk * 512);
        }
        __syncthreads();
        bf16x8 af[4], bfv[4];
        #pragma unroll
        for (int mi = 0; mi < 4; ++mi)
            af[mi] = *(const bf16x8*)&As[(wm * 64 + mi * 16 + ln) * 32 + sw8];
        #pragma unroll
        for (int ni = 0; ni < 4; ++ni)
            bfv[ni] = *(const bf16x8*)&Bs[(wn * 64 + ni * 16 + ln) * 32 + sw8];
        #pragma unroll
        for (int mi = 0; mi < 4; ++mi)
            #pragma unroll
            for (int ni = 0; ni < 4; ++ni)
                acc[mi][ni] = __builtin_amdgcn_mfma_f32_16x16x32_bf16(
                    af[mi], bfv[ni], acc[mi][ni], 0, 0, 0);
    }

    // Assemble [j][o] bf16 tile in LDS (stride 136)
    __syncthreads();
    u16* outl = sm;
    #pragma unroll
    for (int mi = 0; mi < 4; ++mi)
        #pragma unroll
        for (int ni = 0; ni < 4; ++ni) {
            const int jl = wn * 64 + ni * 16 + ln;
            const int ob = wm * 64 + mi * 16 + quad * 4;
            u16x4 u;
            u[0] = f2bf(acc[mi][ni][0]); u[1] = f2bf(acc[mi][ni][1]);
            u[2] = f2bf(acc[mi][ni][2]); u[3] = f2bf(acc[mi][ni][3]);
            *(u16x4*)&outl[jl * 136 + ob] = u;
        }
    __syncthreads();

    if (blockIdx.x < 2) {
        // q tiles: softmax over each 32-col head group, * 1/sqrt(32)
        #pragma unroll
        for (int t = 0; t < 2; ++t) {
            const int idx = t * 256 + tid;
            const int r = idx >> 2, hh = idx & 3;
            const u16* p = &outl[r * 136 + hh * 32];
            float v[32];
            float m = -1e30f;
            #pragma unroll
            for (int g = 0; g < 4; ++g) {
                u16x8 u = *(const u16x8*)(p + g * 8);
                #pragma unroll
                for (int i = 0; i < 8; ++i) {
                    v[g * 8 + i] = bf2f(u[i]);
                    m = fmaxf(m, v[g * 8 + i]);
                }
            }
            float s = 0.f;
            #pragma unroll
            for (int i = 0; i < 32; ++i) { v[i] = __expf(v[i] - m); s += v[i]; }
            const float inv = 0.17677669529663687f / s;
            u16* q = qkv + (size_t)(j0 + r) * 768 + o0 + hh * 32;
            #pragma unroll
            for (int g = 0; g < 4; ++g) {
                u16x8 ov;
                #pragma unroll
                for (int i = 0; i < 8; ++i) ov[i] = f2bf(v[g * 8 + i] * inv);
                *(u16x8*)(q + g * 8) = ov;
            }
        }
    } else {
        #pragma unroll
        for (int r = 0; r < 8; ++r) {
            const int row = r * 16 + (tid >> 4);
            const int cb = (tid & 15) * 8;
            u32x4 v = *(const u32x4*)&outl[row * 136 + cb];
            *(u32x4*)(qkv + (size_t)(j0 + row) * 768 + o0 + cb) = v;
        }
    }
}

// ---------------- S1: online (m,s) partials per k-col, per (fl, j-split) ----
__global__ __launch_bounds__(256) void k_kstat1(const u16* __restrict__ qkv,
                                                float* __restrict__ sp)
{
    const int js = blockIdx.x, fl = blockIdx.y;
    const int tid = threadIdx.x;
    const int s = tid >> 5, g = tid & 31;
    const u16* base = qkv + ((size_t)fl * 4096 + js * 256 + s) * 768 + 256 + g * 8;
    float m[8], sm[8];
    #pragma unroll
    for (int i = 0; i < 8; ++i) { m[i] = -1e30f; sm[i] = 0.f; }
    for (int it = 0; it < 32; ++it) {
        u16x8 u = *(const u16x8*)(base + (size_t)it * 8 * 768);
        #pragma unroll
        for (int i = 0; i < 8; ++i) {
            float v = bf2f(u[i]);
            float nm = fmaxf(m[i], v);
            sm[i] = sm[i] * __expf(m[i] - nm) + __expf(v - nm);
            m[i] = nm;
        }
    }
    __shared__ float Lm[8][256], Ls[8][256];
    #pragma unroll
    for (int i = 0; i < 8; ++i) { Lm[s][g * 8 + i] = m[i]; Ls[s][g * 8 + i] = sm[i]; }
    __syncthreads();
    const int col = tid;
    float M = -1e30f;
    #pragma unroll
    for (int k = 0; k < 8; ++k) M = fmaxf(M, Lm[k][col]);
    float S = 0.f;
    #pragma unroll
    for (int k = 0; k < 8; ++k) S += Ls[k][col] * __expf(Lm[k][col] - M);
    float* o = sp + (((size_t)fl * 16 + js) * 256 + col) * 2;
    o[0] = M; o[1] = S;
}

// ---------------- S2: combine 16 partials -> (M, 1/S) -----------------------
__global__ __launch_bounds__(256) void k_kstat2(const float* __restrict__ sp,
                                                float* __restrict__ stat)
{
    const int fl = blockIdx.x, col = threadIdx.x;
    float mv[16], sv[16];
    float M = -1e30f;
    #pragma unroll
    for (int js = 0; js < 16; ++js) {
        const float* p = sp + (((size_t)fl * 16 + js) * 256 + col) * 2;
        mv[js] = p[0]; sv[js] = p[1];
        M = fmaxf(M, mv[js]);
    }
    float S = 0.f;
    #pragma unroll
    for (int js = 0; js < 16; ++js) S += sv[js] * __expf(mv[js] - M);
    float* o = stat + ((size_t)fl * 256 + col) * 2;
    o[0] = M; o[1] = 1.0f / S;
}

// ---------------- CX: P[h][d][e] += exp(k-M)*v, per (fl, j-split) -----------
__global__ __launch_bounds__(256) void k_ctx(const u16* __restrict__ qkv,
                                             const float* __restrict__ stat,
                                             float* __restrict__ P)
{
    const int js = blockIdx.x, fl = blockIdx.y;
    const int tid = threadIdx.x;
    const int ls = tid >> 5, lg = tid & 31;                  // staging role
    const int h = tid >> 5, dg = (tid >> 3) & 3, eg = tid & 7;  // acc role
    const int d0 = dg * 8, e0 = eg * 4;

    float Mg[8];
    #pragma unroll
    for (int i = 0; i < 8; ++i) Mg[i] = stat[((size_t)fl * 256 + lg * 8 + i) * 2];

    __shared__ float expk[8][264], vbuf[8][264];
    f32x4 acc[8] = {};
    const u16* kbase = qkv + ((size_t)fl * 4096 + js * 256 + ls) * 768 + 256 + lg * 8;

    for (int ch = 0; ch < 32; ++ch) {
        const u16* kp = kbase + (size_t)ch * 8 * 768;
        u16x8 ku = *(const u16x8*)kp;
        u16x8 vu = *(const u16x8*)(kp + 256);
        __syncthreads();
        #pragma unroll
        for (int i = 0; i < 8; ++i) {
            expk[ls][lg * 8 + i] = __expf(bf2f(ku[i]) - Mg[i]);
            vbuf[ls][lg * 8 + i] = bf2f(vu[i]);
        }
        __syncthreads();
        #pragma unroll
        for (int rr = 0; rr < 8; ++rr) {
            f32x4 w0 = *(const f32x4*)&expk[rr][h * 32 + d0];
            f32x4 w1 = *(const f32x4*)&expk[rr][h * 32 + d0 + 4];
            f32x4 vv = *(const f32x4*)&vbuf[rr][h * 32 + e0];
            #pragma unroll
            for (int ei = 0; ei < 4; ++ei) {
                acc[0][ei] = fmaf(w0[0], vv[ei], acc[0][ei]);
                acc[1][ei] = fmaf(w0[1], vv[ei], acc[1][ei]);
                acc[2][ei] = fmaf(w0[2], vv[ei], acc[2][ei]);
                acc[3][ei] = fmaf(w0[3], vv[ei], acc[3][ei]);
                acc[4][ei] = fmaf(w1[0], vv[ei], acc[4][ei]);
                acc[5][ei] = fmaf(w1[1], vv[ei], acc[5][ei]);
                acc[6][ei] = fmaf(w1[2], vv[ei], acc[6][ei]);
                acc[7][ei] = fmaf(w1[3], vv[ei], acc[7][ei]);
            }
        }
    }
    float* o = P + ((size_t)fl * 16 + js) * 8192 + (h * 32 + d0) * 32 + e0;
    #pragma unroll
    for (int di = 0; di < 8; ++di) *(f32x4*)(o + di * 32) = acc[di];
}

// ---------------- W2: sum partials, *invS, fold w_out -> W2 bf16 ------------
__global__ __launch_bounds__(256) void k_w2fold(const float* __restrict__ P,
                                                const float* __restrict__ stat,
                                                const float* __restrict__ w_out,
                                                u16* __restrict__ w2)
{
    const int h = blockIdx.x, fl = blockIdx.y;
    const int tid = threadIdx.x;
    __shared__ float Cs[32 * 33];

    const float* p0 = P + (size_t)fl * 16 * 8192 + h * 1024 + tid * 4;
    f32x4 sum = {0.f, 0.f, 0.f, 0.f};
    #pragma unroll
    for (int js = 0; js < 16; ++js) {
        f32x4 v = *(const f32x4*)(p0 + (size_t)js * 8192);
        sum[0] += v[0]; sum[1] += v[1]; sum[2] += v[2]; sum[3] += v[3];
    }
    const int d = tid >> 3, e4 = (tid & 7) * 4;
    const float inv = stat[((size_t)fl * 256 + h * 32 + d) * 2 + 1];
    Cs[d * 33 + e4 + 0] = sum[0] * inv;
    Cs[d * 33 + e4 + 1] = sum[1] * inv;
    Cs[d * 33 + e4 + 2] = sum[2] * inv;
    Cs[d * 33 + e4 + 3] = sum[3] * inv;
    __syncthreads();

    const int o = tid;
    float a2[32];
    #pragma unroll
    for (int dd = 0; dd < 32; ++dd) a2[dd] = 0.f;
    for (int e = 0; e < 32; ++e) {
        const float wv = w_out[(size_t)o * 256 + h * 32 + e];
        #pragma unroll
        for (int dd = 0; dd < 32; ++dd) a2[dd] = fmaf(wv, Cs[dd * 33 + e], a2[dd]);
    }
    u16* wp = w2 + (size_t)fl * 65536 + (size_t)o * 256 + h * 32;
    #pragma unroll
    for (int g = 0; g < 4; ++g) {
        u16x8 ov;
        #pragma unroll
        for (int i = 0; i < 8; ++i) ov[i] = f2bf(a2[g * 8 + i]);
        *(u16x8*)(wp + g * 8) = ov;
    }
}

// ---------------- K5: out = MFMA(q, W2) + b_out, fp32 direct store ----------
// grid: (o-tiles=2, j-tiles=CF*32)  — o fast-varying so q is fetched once
__global__ __launch_bounds__(256) void k_out_mfma(const u16* __restrict__ qkv,
                                                  const u16* __restrict__ w2,
                                                  const float* __restrict__ b_out,
                                                  float* __restrict__ out, int fr0)
{
    const int tid = threadIdx.x;
    const int lane = tid & 63, wave = tid >> 6;
    const int ln = lane & 15, quad = lane >> 4;
    const int wm = wave & 1, wn = wave >> 1;
    const int j0 = blockIdx.y * 128;   // M tile (q rows, local j)
    const int o0 = blockIdx.x * 128;   // N tile (W2 rows)
    const int fl = j0 >> 12;
    const int frame = fr0 + fl, b = frame >> 4, f = frame & 15;
    const int nb = j0 & 4095;
    const u16* w2f = w2 + (size_t)fl * 65536;

    __shared__ __align__(16) u16 sm[8192];
    u16* As = sm;
    u16* Bs = sm + 4096;

    f32x4 acc[4][4] = {};
    const int lrow = lane >> 2;
    const int lk8 = ((lane & 3) ^ ((lrow >> 1) & 3)) * 8;   // pre-swizzled src
    const int sw8 = (quad ^ ((ln >> 1) & 3)) * 8;           // swizzled ds_read

    for (int kk = 0; kk < 256; kk += 32) {
        __syncthreads();
        #pragma unroll
        for (int p = 0; p < 2; ++p) {
            const int chunk = wave * 2 + p;
            const int r = chunk * 16 + lrow;
            async16(qkv + (size_t)(j0 + r) * 768 + kk + lk8, As + chunk * 512);
            async16(w2f + (size_t)(o0 + r) * 256 + kk + lk8, Bs + chunk * 512);
        }
        __syncthreads();
        bf16x8 af[4], bfv[4];
        #pragma unroll
        for (int mi = 0; mi < 4; ++mi)
            af[mi] = *(const bf16x8*)&As[(wm * 64 + mi * 16 + ln) * 32 + sw8];
        #pragma unroll
        for (int ni = 0; ni < 4; ++ni)
            bfv[ni] = *(const bf16x8*)&Bs[(wn * 64 + ni * 16 + ln) * 32 + sw8];
        #pragma unroll
        for (int mi = 0; mi < 4; ++mi)
            #pragma unroll
            for (int ni = 0; ni < 4; ++ni)
                acc[mi][ni] = __builtin_amdgcn_mfma_f32_16x16x32_bf16(
                    af[mi], bfv[ni], acc[mi][ni], 0, 0, 0);
    }

    float* obase = out + (size_t)b * XB_STRIDE + (size_t)f * 4096;
    #pragma unroll
    for (int ni = 0; ni < 4; ++ni) {
        const int o = o0 + wn * 64 + ni * 16 + ln;
        const float bias = b_out[o];
        #pragma unroll
        for (int mi = 0; mi < 4; ++mi) {
            const int jn = nb + wm * 64 + mi * 16 + quad * 4;
            f32x4 v = acc[mi][ni];
            v[0] += bias; v[1] += bias; v[2] += bias; v[3] += bias;
            *(f32x4*)(obase + (size_t)o * XCH_STRIDE + jn) = v;
        }
    }
}

// ---------------------------------------------------------------------------
extern "C" void kernel_launch(void* const* d_in, const int* in_sizes, int n_in,
                              void* d_out, int out_size, void* d_ws, size_t ws_size,
                              hipStream_t stream)
{
    const float* x     = (const float*)d_in[0];
    const float* w_qkv = (const float*)d_in[1];
    const float* w_out = (const float*)d_in[2];
    const float* b_out = (const float*)d_in[3];
    float* out = (float*)d_out;

    // ws per frame: xbf 2MB + qkv 6MB + w2 128KB + sp 32KB + stat 2KB + P 512KB
    const size_t per_frame = (size_t)4096 * 256 * 2 + (size_t)4096 * 768 * 2
                           + 65536 * 2 + 16 * 512 * 4 + 512 * 4 + 16 * 8192 * 4;
    const size_t wq_bytes = 768 * 256 * 2;
    int CF = 32;
    while (CF > 1 && (size_t)CF * per_frame + wq_bytes > ws_size) CF >>= 1;

    u16* wq_bf  = (u16*)d_ws;
    u16* xbf    = wq_bf + 768 * 256;
    u16* qkv    = xbf + (size_t)CF * 4096 * 256;
    u16* w2     = qkv + (size_t)CF * 4096 * 768;
    float* sp   = (float*)(w2 + (size_t)CF * 65536);
    float* stat = sp + (size_t)CF * 16 * 256 * 2;
    float* P    = stat + (size_t)CF * 256 * 2;

    k_cvt_w<<<96, 256, 0, stream>>>(w_qkv, wq_bf);
    for (int fr0 = 0; fr0 < 32; fr0 += CF) {
        k_cvt_x   <<<dim3(64, 4, CF), 256, 0, stream>>>(x, xbf, fr0);
        k_qkv_mfma<<<dim3(6, CF * 32), 256, 0, stream>>>(xbf, wq_bf, qkv);
        k_kstat1  <<<dim3(16, CF), 256, 0, stream>>>(qkv, sp);
        k_kstat2  <<<CF, 256, 0, stream>>>(sp, stat);
        k_ctx     <<<dim3(16, CF), 256, 0, stream>>>(qkv, stat, P);
        k_w2fold  <<<dim3(8, CF), 256, 0, stream>>>(P, stat, w_out, w2);
        k_out_mfma<<<dim3(2, CF * 32), 256, 0, stream>>>(qkv, w2, b_out, out, fr0);
    }
}

// Round 2
// 482.631 us; speedup vs baseline: 1.0072x; 1.0015x over previous
//
#include <hip/hip_runtime.h>
#include <cmath>

// ---------------------------------------------------------------------------
// SpatialLinearAttention — bf16 MFMA GEMMs + fused softmax/context chain.
//   x:(2,256,16,64,64) f32, w_qkv:(768,256) f32, w_out:(256,256) f32, b_out:(256,)
// Per chunk of CF frames (j = fl*4096 + n):
//   C0: xbf_t[j][c] = bf16(x^T)                      (k-contiguous)
//   C1: wq_bf = bf16(w_qkv)                          (once)
//   K1: qkv_t[j][o] = MFMA(wq[o][c], xbf[j][c]); q tiles (o<256) get the
//       d-softmax (*1/sqrt(32)) fused in the epilogue.  k,v stored raw bf16.
//   S1: k_kstat1: per (fl, j-split): online (m,s) partials per k-col (256)
//   S2: k_kstat2: combine 16 partials -> (M, 1/S) per (fl, k-col)
//   CX: k_ctx: per (fl, j-split): P[h][d][e] += exp(k[d,j]-M_d) * v[e,j]
//   W2: k_w2fold: C = invS_d * sum_js P; W2[o][h*32+d] = sum_e w_out[o][..e]*C[d][e]
//   K5: out = MFMA(q[j][c2], W2[o][c2]) + b_out, fp32 direct store
//
// R1: LDS XOR swizzle on MFMA staging tiles (bank conflicts 8.4M -> 2.1M, OK).
// R2: XCD-chunked bijective block swizzle on both MFMA kernels. R1's grid
//     transpose failed (FETCH stayed 199MB = 3x intrinsic): consecutive
//     blockIdx round-robin across the 8 XCDs, so co-reading blocks sat on
//     different private L2s. Now: 1-D grid, xcd = bid&7, each XCD owns a
//     contiguous run of j-tiles with all o-tiles of a j-tile consecutive
//     WITHIN the XCD -> each xbf/q slice fetched once into one L2.
// ---------------------------------------------------------------------------

typedef unsigned short u16;
typedef __attribute__((ext_vector_type(4))) unsigned short u16x4;
typedef __attribute__((ext_vector_type(8))) unsigned short u16x8;
typedef __attribute__((ext_vector_type(4))) unsigned int   u32x4;
typedef __attribute__((ext_vector_type(8))) short bf16x8;
typedef __attribute__((ext_vector_type(4))) float f32x4;

#define XCH_STRIDE 65536    // x stride over c: 16*4096
#define XB_STRIDE  16777216 // x stride over b: 256*16*4096

__device__ __forceinline__ float bf2f(u16 u) {
    union { unsigned int i; float f; } w; w.i = ((unsigned int)u) << 16; return w.f;
}
__device__ __forceinline__ u16 f2bf(float f) {
    union { float f; unsigned int i; } w; w.f = f;
    return (u16)((w.i + 0x7FFFu + ((w.i >> 16) & 1u)) >> 16);
}
__device__ __forceinline__ void async16(const void* g, void* l) {
    __builtin_amdgcn_global_load_lds(
        (const __attribute__((address_space(1))) unsigned int*)g,
        (__attribute__((address_space(3))) unsigned int*)l, 16, 0, 0);
}

// ---------------- C0: x (b,c,f,n) f32 -> xbf_t[(fl,n)][c] bf16 --------------
__global__ __launch_bounds__(256) void k_cvt_x(const float* __restrict__ x,
                                               u16* __restrict__ xbf, int fr0)
{
    const int tid = threadIdx.x;
    const int n0 = blockIdx.x * 64;
    const int c0 = blockIdx.y * 64;
    const int fl = blockIdx.z;
    const int frame = fr0 + fl, b = frame >> 4, f = frame & 15;
    const float* xb = x + (size_t)b * XB_STRIDE + (size_t)f * 4096;
    __shared__ float T[64][65];
    const int nn = tid & 63, cq = tid >> 6;
    #pragma unroll
    for (int r = 0; r < 16; ++r) {
        const int cl = r * 4 + cq;
        T[cl][nn] = xb[(size_t)(c0 + cl) * XCH_STRIDE + n0 + nn];
    }
    __syncthreads();
    const int jl = tid >> 2, c16 = (tid & 3) * 16;
    u16* dst = xbf + ((size_t)fl * 4096 + n0 + jl) * 256 + c0 + c16;
    u16x8 a, bv;
    #pragma unroll
    for (int i = 0; i < 8; ++i) a[i] = f2bf(T[c16 + i][jl]);
    #pragma unroll
    for (int i = 0; i < 8; ++i) bv[i] = f2bf(T[c16 + 8 + i][jl]);
    *(u16x8*)dst = a;
    *(u16x8*)(dst + 8) = bv;
}

// ---------------- C1: w_qkv f32 -> bf16 -------------------------------------
__global__ __launch_bounds__(256) void k_cvt_w(const float* __restrict__ w,
                                               u16* __restrict__ wbf)
{
    const int i = (blockIdx.x * 256 + threadIdx.x) * 8;
    u16x8 o;
    #pragma unroll
    for (int j = 0; j < 8; ++j) o[j] = f2bf(w[i + j]);
    *(u16x8*)(wbf + i) = o;
}

// ---------------- K1: qkv_t[j][o] MFMA, q-softmax fused in epilogue ---------
// grid: 1-D, CF*32*6 blocks; XCD-chunked swizzle, o fastest within XCD
__global__ __launch_bounds__(256) void k_qkv_mfma(const u16* __restrict__ xbf,
                                                  const u16* __restrict__ wq,
                                                  u16* __restrict__ qkv)
{
    const int tid = threadIdx.x;
    const int lane = tid & 63, wave = tid >> 6;
    const int ln = lane & 15, quad = lane >> 4;
    const int wm = wave & 1, wn = wave >> 1;

    // XCD-chunked bijective swizzle (gridDim.x always % 8 == 0 here:
    // 6*32*CF = 192*CF). xcd = bid&7 owns newid range [xcd*chunk, ...).
    const int chunk = gridDim.x >> 3;
    const int newid = (blockIdx.x & 7) * chunk + (blockIdx.x >> 3);
    const int o0 = (newid % 6) * 128;   // M tile (wq rows) — fastest
    const int j0 = (newid / 6) * 128;   // N tile (x rows)

    __shared__ __align__(16) u16 sm[128 * 136];  // staging + out-tile overlaid
    u16* As = sm;             // [128 o][32 k]   (16B slots XOR-swizzled)
    u16* Bs = sm + 4096;      // [128 j][32 k]

    f32x4 acc[4][4] = {};
    const int lrow = lane >> 2;
    // pre-swizzled global source: LDS slot (r, c) must hold chunk c^((r>>1)&3)
    const int lk8 = ((lane & 3) ^ ((lrow >> 1) & 3)) * 8;
    // fragment-read swizzle: same XOR; (row>>1)&3 == (ln>>1)&3 (row = 16m+ln)
    const int sw8 = (quad ^ ((ln >> 1) & 3)) * 8;

    for (int kk = 0; kk < 256; kk += 32) {
        __syncthreads();
        #pragma unroll
        for (int p = 0; p < 2; ++p) {
            const int ch = wave * 2 + p;
            const int r = ch * 16 + lrow;
            async16(wq  + (size_t)(o0 + r) * 256 + kk + lk8, As + ch * 512);
            async16(xbf + (size_t)(j0 + r) * 256 + kk + lk8, Bs + ch * 512);
        }
        __syncthreads();
        bf16x8 af[4], bfv[4];
        #pragma unroll
        for (int mi = 0; mi < 4; ++mi)
            af[mi] = *(const bf16x8*)&As[(wm * 64 + mi * 16 + ln) * 32 + sw8];
        #pragma unroll
        for (int ni = 0; ni < 4; ++ni)
            bfv[ni] = *(const bf16x8*)&Bs[(wn * 64 + ni * 16 + ln) * 32 + sw8];
        #pragma unroll
        for (int mi = 0; mi < 4; ++mi)
            #pragma unroll
            for (int ni = 0; ni < 4; ++ni)
                acc[mi][ni] = __builtin_amdgcn_mfma_f32_16x16x32_bf16(
                    af[mi], bfv[ni], acc[mi][ni], 0, 0, 0);
    }

    // Assemble [j][o] bf16 tile in LDS (stride 136)
    __syncthreads();
    u16* outl = sm;
    #pragma unroll
    for (int mi = 0; mi < 4; ++mi)
        #pragma unroll
        for (int ni = 0; ni < 4; ++ni) {
            const int jl = wn * 64 + ni * 16 + ln;
            const int ob = wm * 64 + mi * 16 + quad * 4;
            u16x4 u;
            u[0] = f2bf(acc[mi][ni][0]); u[1] = f2bf(acc[mi][ni][1]);
            u[2] = f2bf(acc[mi][ni][2]); u[3] = f2bf(acc[mi][ni][3]);
            *(u16x4*)&outl[jl * 136 + ob] = u;
        }
    __syncthreads();

    if (o0 < 256) {
        // q tiles: softmax over each 32-col head group, * 1/sqrt(32)
        #pragma unroll
        for (int t = 0; t < 2; ++t) {
            const int idx = t * 256 + tid;
            const int r = idx >> 2, hh = idx & 3;
            const u16* p = &outl[r * 136 + hh * 32];
            float v[32];
            float m = -1e30f;
            #pragma unroll
            for (int g = 0; g < 4; ++g) {
                u16x8 u = *(const u16x8*)(p + g * 8);
                #pragma unroll
                for (int i = 0; i < 8; ++i) {
                    v[g * 8 + i] = bf2f(u[i]);
                    m = fmaxf(m, v[g * 8 + i]);
                }
            }
            float s = 0.f;
            #pragma unroll
            for (int i = 0; i < 32; ++i) { v[i] = __expf(v[i] - m); s += v[i]; }
            const float inv = 0.17677669529663687f / s;
            u16* q = qkv + (size_t)(j0 + r) * 768 + o0 + hh * 32;
            #pragma unroll
            for (int g = 0; g < 4; ++g) {
                u16x8 ov;
                #pragma unroll
                for (int i = 0; i < 8; ++i) ov[i] = f2bf(v[g * 8 + i] * inv);
                *(u16x8*)(q + g * 8) = ov;
            }
        }
    } else {
        #pragma unroll
        for (int r = 0; r < 8; ++r) {
            const int row = r * 16 + (tid >> 4);
            const int cb = (tid & 15) * 8;
            u32x4 v = *(const u32x4*)&outl[row * 136 + cb];
            *(u32x4*)(qkv + (size_t)(j0 + row) * 768 + o0 + cb) = v;
        }
    }
}

// ---------------- S1: online (m,s) partials per k-col, per (fl, j-split) ----
__global__ __launch_bounds__(256) void k_kstat1(const u16* __restrict__ qkv,
                                                float* __restrict__ sp)
{
    const int js = blockIdx.x, fl = blockIdx.y;
    const int tid = threadIdx.x;
    const int s = tid >> 5, g = tid & 31;
    const u16* base = qkv + ((size_t)fl * 4096 + js * 256 + s) * 768 + 256 + g * 8;
    float m[8], sm[8];
    #pragma unroll
    for (int i = 0; i < 8; ++i) { m[i] = -1e30f; sm[i] = 0.f; }
    for (int it = 0; it < 32; ++it) {
        u16x8 u = *(const u16x8*)(base + (size_t)it * 8 * 768);
        #pragma unroll
        for (int i = 0; i < 8; ++i) {
            float v = bf2f(u[i]);
            float nm = fmaxf(m[i], v);
            sm[i] = sm[i] * __expf(m[i] - nm) + __expf(v - nm);
            m[i] = nm;
        }
    }
    __shared__ float Lm[8][256], Ls[8][256];
    #pragma unroll
    for (int i = 0; i < 8; ++i) { Lm[s][g * 8 + i] = m[i]; Ls[s][g * 8 + i] = sm[i]; }
    __syncthreads();
    const int col = tid;
    float M = -1e30f;
    #pragma unroll
    for (int k = 0; k < 8; ++k) M = fmaxf(M, Lm[k][col]);
    float S = 0.f;
    #pragma unroll
    for (int k = 0; k < 8; ++k) S += Ls[k][col] * __expf(Lm[k][col] - M);
    float* o = sp + (((size_t)fl * 16 + js) * 256 + col) * 2;
    o[0] = M; o[1] = S;
}

// ---------------- S2: combine 16 partials -> (M, 1/S) -----------------------
__global__ __launch_bounds__(256) void k_kstat2(const float* __restrict__ sp,
                                                float* __restrict__ stat)
{
    const int fl = blockIdx.x, col = threadIdx.x;
    float mv[16], sv[16];
    float M = -1e30f;
    #pragma unroll
    for (int js = 0; js < 16; ++js) {
        const float* p = sp + (((size_t)fl * 16 + js) * 256 + col) * 2;
        mv[js] = p[0]; sv[js] = p[1];
        M = fmaxf(M, mv[js]);
    }
    float S = 0.f;
    #pragma unroll
    for (int js = 0; js < 16; ++js) S += sv[js] * __expf(mv[js] - M);
    float* o = stat + ((size_t)fl * 256 + col) * 2;
    o[0] = M; o[1] = 1.0f / S;
}

// ---------------- CX: P[h][d][e] += exp(k-M)*v, per (fl, j-split) -----------
__global__ __launch_bounds__(256) void k_ctx(const u16* __restrict__ qkv,
                                             const float* __restrict__ stat,
                                             float* __restrict__ P)
{
    const int js = blockIdx.x, fl = blockIdx.y;
    const int tid = threadIdx.x;
    const int ls = tid >> 5, lg = tid & 31;                  // staging role
    const int h = tid >> 5, dg = (tid >> 3) & 3, eg = tid & 7;  // acc role
    const int d0 = dg * 8, e0 = eg * 4;

    float Mg[8];
    #pragma unroll
    for (int i = 0; i < 8; ++i) Mg[i] = stat[((size_t)fl * 256 + lg * 8 + i) * 2];

    __shared__ float expk[8][264], vbuf[8][264];
    f32x4 acc[8] = {};
    const u16* kbase = qkv + ((size_t)fl * 4096 + js * 256 + ls) * 768 + 256 + lg * 8;

    for (int ch = 0; ch < 32; ++ch) {
        const u16* kp = kbase + (size_t)ch * 8 * 768;
        u16x8 ku = *(const u16x8*)kp;
        u16x8 vu = *(const u16x8*)(kp + 256);
        __syncthreads();
        #pragma unroll
        for (int i = 0; i < 8; ++i) {
            expk[ls][lg * 8 + i] = __expf(bf2f(ku[i]) - Mg[i]);
            vbuf[ls][lg * 8 + i] = bf2f(vu[i]);
        }
        __syncthreads();
        #pragma unroll
        for (int rr = 0; rr < 8; ++rr) {
            f32x4 w0 = *(const f32x4*)&expk[rr][h * 32 + d0];
            f32x4 w1 = *(const f32x4*)&expk[rr][h * 32 + d0 + 4];
            f32x4 vv = *(const f32x4*)&vbuf[rr][h * 32 + e0];
            #pragma unroll
            for (int ei = 0; ei < 4; ++ei) {
                acc[0][ei] = fmaf(w0[0], vv[ei], acc[0][ei]);
                acc[1][ei] = fmaf(w0[1], vv[ei], acc[1][ei]);
                acc[2][ei] = fmaf(w0[2], vv[ei], acc[2][ei]);
                acc[3][ei] = fmaf(w0[3], vv[ei], acc[3][ei]);
                acc[4][ei] = fmaf(w1[0], vv[ei], acc[4][ei]);
                acc[5][ei] = fmaf(w1[1], vv[ei], acc[5][ei]);
                acc[6][ei] = fmaf(w1[2], vv[ei], acc[6][ei]);
                acc[7][ei] = fmaf(w1[3], vv[ei], acc[7][ei]);
            }
        }
    }
    float* o = P + ((size_t)fl * 16 + js) * 8192 + (h * 32 + d0) * 32 + e0;
    #pragma unroll
    for (int di = 0; di < 8; ++di) *(f32x4*)(o + di * 32) = acc[di];
}

// ---------------- W2: sum partials, *invS, fold w_out -> W2 bf16 ------------
__global__ __launch_bounds__(256) void k_w2fold(const float* __restrict__ P,
                                                const float* __restrict__ stat,
                                                const float* __restrict__ w_out,
                                                u16* __restrict__ w2)
{
    const int h = blockIdx.x, fl = blockIdx.y;
    const int tid = threadIdx.x;
    __shared__ float Cs[32 * 33];

    const float* p0 = P + (size_t)fl * 16 * 8192 + h * 1024 + tid * 4;
    f32x4 sum = {0.f, 0.f, 0.f, 0.f};
    #pragma unroll
    for (int js = 0; js < 16; ++js) {
        f32x4 v = *(const f32x4*)(p0 + (size_t)js * 8192);
        sum[0] += v[0]; sum[1] += v[1]; sum[2] += v[2]; sum[3] += v[3];
    }
    const int d = tid >> 3, e4 = (tid & 7) * 4;
    const float inv = stat[((size_t)fl * 256 + h * 32 + d) * 2 + 1];
    Cs[d * 33 + e4 + 0] = sum[0] * inv;
    Cs[d * 33 + e4 + 1] = sum[1] * inv;
    Cs[d * 33 + e4 + 2] = sum[2] * inv;
    Cs[d * 33 + e4 + 3] = sum[3] * inv;
    __syncthreads();

    const int o = tid;
    float a2[32];
    #pragma unroll
    for (int dd = 0; dd < 32; ++dd) a2[dd] = 0.f;
    for (int e = 0; e < 32; ++e) {
        const float wv = w_out[(size_t)o * 256 + h * 32 + e];
        #pragma unroll
        for (int dd = 0; dd < 32; ++dd) a2[dd] = fmaf(wv, Cs[dd * 33 + e], a2[dd]);
    }
    u16* wp = w2 + (size_t)fl * 65536 + (size_t)o * 256 + h * 32;
    #pragma unroll
    for (int g = 0; g < 4; ++g) {
        u16x8 ov;
        #pragma unroll
        for (int i = 0; i < 8; ++i) ov[i] = f2bf(a2[g * 8 + i]);
        *(u16x8*)(wp + g * 8) = ov;
    }
}

// ---------------- K5: out = MFMA(q, W2) + b_out, fp32 direct store ----------
// grid: 1-D, CF*32*2 blocks; XCD-chunked swizzle, o fastest within XCD
__global__ __launch_bounds__(256) void k_out_mfma(const u16* __restrict__ qkv,
                                                  const u16* __restrict__ w2,
                                                  const float* __restrict__ b_out,
                                                  float* __restrict__ out, int fr0)
{
    const int tid = threadIdx.x;
    const int lane = tid & 63, wave = tid >> 6;
    const int ln = lane & 15, quad = lane >> 4;
    const int wm = wave & 1, wn = wave >> 1;

    const int chunk = gridDim.x >> 3;
    const int newid = (blockIdx.x & 7) * chunk + (blockIdx.x >> 3);
    const int o0 = (newid & 1) * 128;   // N tile (W2 rows) — fastest
    const int j0 = (newid >> 1) * 128;  // M tile (q rows, local j)

    const int fl = j0 >> 12;
    const int frame = fr0 + fl, b = frame >> 4, f = frame & 15;
    const int nb = j0 & 4095;
    const u16* w2f = w2 + (size_t)fl * 65536;

    __shared__ __align__(16) u16 sm[8192];
    u16* As = sm;
    u16* Bs = sm + 4096;

    f32x4 acc[4][4] = {};
    const int lrow = lane >> 2;
    const int lk8 = ((lane & 3) ^ ((lrow >> 1) & 3)) * 8;   // pre-swizzled src
    const int sw8 = (quad ^ ((ln >> 1) & 3)) * 8;           // swizzled ds_read

    for (int kk = 0; kk < 256; kk += 32) {
        __syncthreads();
        #pragma unroll
        for (int p = 0; p < 2; ++p) {
            const int ch = wave * 2 + p;
            const int r = ch * 16 + lrow;
            async16(qkv + (size_t)(j0 + r) * 768 + kk + lk8, As + ch * 512);
            async16(w2f + (size_t)(o0 + r) * 256 + kk + lk8, Bs + ch * 512);
        }
        __syncthreads();
        bf16x8 af[4], bfv[4];
        #pragma unroll
        for (int mi = 0; mi < 4; ++mi)
            af[mi] = *(const bf16x8*)&As[(wm * 64 + mi * 16 + ln) * 32 + sw8];
        #pragma unroll
        for (int ni = 0; ni < 4; ++ni)
            bfv[ni] = *(const bf16x8*)&Bs[(wn * 64 + ni * 16 + ln) * 32 + sw8];
        #pragma unroll
        for (int mi = 0; mi < 4; ++mi)
            #pragma unroll
            for (int ni = 0; ni < 4; ++ni)
                acc[mi][ni] = __builtin_amdgcn_mfma_f32_16x16x32_bf16(
                    af[mi], bfv[ni], acc[mi][ni], 0, 0, 0);
    }

    float* obase = out + (size_t)b * XB_STRIDE + (size_t)f * 4096;
    #pragma unroll
    for (int ni = 0; ni < 4; ++ni) {
        const int o = o0 + wn * 64 + ni * 16 + ln;
        const float bias = b_out[o];
        #pragma unroll
        for (int mi = 0; mi < 4; ++mi) {
            const int jn = nb + wm * 64 + mi * 16 + quad * 4;
            f32x4 v = acc[mi][ni];
            v[0] += bias; v[1] += bias; v[2] += bias; v[3] += bias;
            *(f32x4*)(obase + (size_t)o * XCH_STRIDE + jn) = v;
        }
    }
}

// ---------------------------------------------------------------------------
extern "C" void kernel_launch(void* const* d_in, const int* in_sizes, int n_in,
                              void* d_out, int out_size, void* d_ws, size_t ws_size,
                              hipStream_t stream)
{
    const float* x     = (const float*)d_in[0];
    const float* w_qkv = (const float*)d_in[1];
    const float* w_out = (const float*)d_in[2];
    const float* b_out = (const float*)d_in[3];
    float* out = (float*)d_out;

    // ws per frame: xbf 2MB + qkv 6MB + w2 128KB + sp 32KB + stat 2KB + P 512KB
    const size_t per_frame = (size_t)4096 * 256 * 2 + (size_t)4096 * 768 * 2
                           + 65536 * 2 + 16 * 512 * 4 + 512 * 4 + 16 * 8192 * 4;
    const size_t wq_bytes = 768 * 256 * 2;
    int CF = 32;
    while (CF > 1 && (size_t)CF * per_frame + wq_bytes > ws_size) CF >>= 1;

    u16* wq_bf  = (u16*)d_ws;
    u16* xbf    = wq_bf + 768 * 256;
    u16* qkv    = xbf + (size_t)CF * 4096 * 256;
    u16* w2     = qkv + (size_t)CF * 4096 * 768;
    float* sp   = (float*)(w2 + (size_t)CF * 65536);
    float* stat = sp + (size_t)CF * 16 * 256 * 2;
    float* P    = stat + (size_t)CF * 256 * 2;

    k_cvt_w<<<96, 256, 0, stream>>>(w_qkv, wq_bf);
    for (int fr0 = 0; fr0 < 32; fr0 += CF) {
        k_cvt_x   <<<dim3(64, 4, CF), 256, 0, stream>>>(x, xbf, fr0);
        k_qkv_mfma<<<CF * 32 * 6, 256, 0, stream>>>(xbf, wq_bf, qkv);
        k_kstat1  <<<dim3(16, CF), 256, 0, stream>>>(qkv, sp);
        k_kstat2  <<<CF, 256, 0, stream>>>(sp, stat);
        k_ctx     <<<dim3(16, CF), 256, 0, stream>>>(qkv, stat, P);
        k_w2fold  <<<dim3(8, CF), 256, 0, stream>>>(P, stat, w_out, w2);
        k_out_mfma<<<CF * 32 * 2, 256, 0, stream>>>(qkv, w2, b_out, out, fr0);
    }
}

// Round 3
// 476.710 us; speedup vs baseline: 1.0197x; 1.0124x over previous
//
#include <hip/hip_runtime.h>
#include <cmath>

// ---------------------------------------------------------------------------
// SpatialLinearAttention — bf16 MFMA GEMMs + fused softmax/context chain.
//   x:(2,256,16,64,64) f32, w_qkv:(768,256) f32, w_out:(256,256) f32, b_out:(256,)
// Per chunk of CF frames (j = fl*4096 + n):
//   C0: xbf_t[j][c] = bf16(x^T)                      (k-contiguous)
//   C1: wq_bf = bf16(w_qkv)                          (once)
//   K1: qkv_t[j][o] = MFMA(wq[o][c], xbf[j][c]); q tiles (o<256) get the
//       d-softmax (*1/sqrt(32)) fused in the epilogue.  k,v stored raw bf16.
//   S1: k_kstat1: per (fl, j-split): online (m,s) partials per k-col (256)
//   S2: k_kstat2: combine 16 partials -> (M, 1/S) per (fl, k-col)
//   CX: k_ctx: per (fl, j-split): P[h][d][e] += exp(k[d,j]-M_d) * v[e,j]
//   W2: k_w2fold: C = invS_d * sum_js P; W2[o][h*32+d] = sum_e w_out[o][..e]*C[d][e]
//   K5: out = MFMA(q[j][c2], W2[o][c2]) + b_out, fp32 direct store
//
// R1: LDS XOR swizzle on MFMA staging tiles (bank conflicts 8.4M -> 2.1M, OK).
// R2: XCD-chunked bijective block swizzle (FETCH 199MB -> 35MB, OK) — kernel
//     now structure-bound (2.3 TB/s, MfmaUtil 20%).
// R3: 2-phase double-buffered K-loop (catalog T3 minimum form) in both MFMA
//     kernels: STAGE(next) issued BEFORE ds_read+MFMA of cur; one raw
//     s_barrier + asm vmcnt(0) per K-step (was: 2 barriers + full drain
//     BEFORE compute). Loads overlap compute; barrier count halves.
// ---------------------------------------------------------------------------

typedef unsigned short u16;
typedef __attribute__((ext_vector_type(4))) unsigned short u16x4;
typedef __attribute__((ext_vector_type(8))) unsigned short u16x8;
typedef __attribute__((ext_vector_type(4))) unsigned int   u32x4;
typedef __attribute__((ext_vector_type(8))) short bf16x8;
typedef __attribute__((ext_vector_type(4))) float f32x4;

#define XCH_STRIDE 65536    // x stride over c: 16*4096
#define XB_STRIDE  16777216 // x stride over b: 256*16*4096

__device__ __forceinline__ float bf2f(u16 u) {
    union { unsigned int i; float f; } w; w.i = ((unsigned int)u) << 16; return w.f;
}
__device__ __forceinline__ u16 f2bf(float f) {
    union { float f; unsigned int i; } w; w.f = f;
    return (u16)((w.i + 0x7FFFu + ((w.i >> 16) & 1u)) >> 16);
}
__device__ __forceinline__ void async16(const void* g, void* l) {
    __builtin_amdgcn_global_load_lds(
        (const __attribute__((address_space(1))) unsigned int*)g,
        (__attribute__((address_space(3))) unsigned int*)l, 16, 0, 0);
}

// ---------------- C0: x (b,c,f,n) f32 -> xbf_t[(fl,n)][c] bf16 --------------
__global__ __launch_bounds__(256) void k_cvt_x(const float* __restrict__ x,
                                               u16* __restrict__ xbf, int fr0)
{
    const int tid = threadIdx.x;
    const int n0 = blockIdx.x * 64;
    const int c0 = blockIdx.y * 64;
    const int fl = blockIdx.z;
    const int frame = fr0 + fl, b = frame >> 4, f = frame & 15;
    const float* xb = x + (size_t)b * XB_STRIDE + (size_t)f * 4096;
    __shared__ float T[64][65];
    const int nn = tid & 63, cq = tid >> 6;
    #pragma unroll
    for (int r = 0; r < 16; ++r) {
        const int cl = r * 4 + cq;
        T[cl][nn] = xb[(size_t)(c0 + cl) * XCH_STRIDE + n0 + nn];
    }
    __syncthreads();
    const int jl = tid >> 2, c16 = (tid & 3) * 16;
    u16* dst = xbf + ((size_t)fl * 4096 + n0 + jl) * 256 + c0 + c16;
    u16x8 a, bv;
    #pragma unroll
    for (int i = 0; i < 8; ++i) a[i] = f2bf(T[c16 + i][jl]);
    #pragma unroll
    for (int i = 0; i < 8; ++i) bv[i] = f2bf(T[c16 + 8 + i][jl]);
    *(u16x8*)dst = a;
    *(u16x8*)(dst + 8) = bv;
}

// ---------------- C1: w_qkv f32 -> bf16 -------------------------------------
__global__ __launch_bounds__(256) void k_cvt_w(const float* __restrict__ w,
                                               u16* __restrict__ wbf)
{
    const int i = (blockIdx.x * 256 + threadIdx.x) * 8;
    u16x8 o;
    #pragma unroll
    for (int j = 0; j < 8; ++j) o[j] = f2bf(w[i + j]);
    *(u16x8*)(wbf + i) = o;
}

// ---------------- K1: qkv_t[j][o] MFMA, q-softmax fused in epilogue ---------
// grid: 1-D, CF*32*6 blocks; XCD-chunked swizzle, o fastest within XCD
__global__ __launch_bounds__(256) void k_qkv_mfma(const u16* __restrict__ xbf,
                                                  const u16* __restrict__ wq,
                                                  u16* __restrict__ qkv)
{
    const int tid = threadIdx.x;
    const int lane = tid & 63, wave = tid >> 6;
    const int ln = lane & 15, quad = lane >> 4;
    const int wm = wave & 1, wn = wave >> 1;

    // XCD-chunked bijective swizzle (gridDim.x % 8 == 0: 192*CF)
    const int chunk = gridDim.x >> 3;
    const int newid = (blockIdx.x & 7) * chunk + (blockIdx.x >> 3);
    const int o0 = (newid % 6) * 128;   // M tile (wq rows) — fastest
    const int j0 = (newid / 6) * 128;   // N tile (x rows)

    // LDS: double-buffered staging (2 x 16KB) overlaid with 34.8KB out-tile
    __shared__ __align__(16) u16 sm[128 * 136];

    f32x4 acc[4][4] = {};
    const int lrow = lane >> 2;
    // pre-swizzled global source: LDS slot (r, c) must hold chunk c^((r>>1)&3)
    const int lk8 = ((lane & 3) ^ ((lrow >> 1) & 3)) * 8;
    // fragment-read swizzle: same XOR; (row>>1)&3 == (ln>>1)&3 (row = 16m+ln)
    const int sw8 = (quad ^ ((ln >> 1) & 3)) * 8;

    const u16* gA = wq  + (size_t)o0 * 256;
    const u16* gB = xbf + (size_t)j0 * 256;
    const int r0 = wave * 32 + lrow;        // chunk = wave*2+p -> rows r0, r0+16

    // prologue: stage K-step 0 into buf 0
    {
        u16* A = sm;      u16* B = sm + 4096;
        async16(gA + (size_t)r0 * 256 + lk8,          A + (wave*2) * 512);
        async16(gB + (size_t)r0 * 256 + lk8,          B + (wave*2) * 512);
        async16(gA + (size_t)(r0+16) * 256 + lk8,     A + (wave*2+1) * 512);
        async16(gB + (size_t)(r0+16) * 256 + lk8,     B + (wave*2+1) * 512);
    }
    asm volatile("s_waitcnt vmcnt(0)" ::: "memory");
    __builtin_amdgcn_s_barrier();

    #pragma unroll
    for (int t = 0; t < 8; ++t) {
        const int cur = t & 1;
        if (t < 7) {  // issue next-tile loads (fly under ds_read+MFMA)
            u16* A = sm + (cur ^ 1) * 8192;
            u16* B = A + 4096;
            const int kk = (t + 1) * 32;
            async16(gA + (size_t)r0 * 256 + kk + lk8,      A + (wave*2) * 512);
            async16(gB + (size_t)r0 * 256 + kk + lk8,      B + (wave*2) * 512);
            async16(gA + (size_t)(r0+16) * 256 + kk + lk8, A + (wave*2+1) * 512);
            async16(gB + (size_t)(r0+16) * 256 + kk + lk8, B + (wave*2+1) * 512);
        }
        const u16* As = sm + cur * 8192;
        const u16* Bs = As + 4096;
        bf16x8 af[4], bfv[4];
        #pragma unroll
        for (int mi = 0; mi < 4; ++mi)
            af[mi] = *(const bf16x8*)&As[(wm * 64 + mi * 16 + ln) * 32 + sw8];
        #pragma unroll
        for (int ni = 0; ni < 4; ++ni)
            bfv[ni] = *(const bf16x8*)&Bs[(wn * 64 + ni * 16 + ln) * 32 + sw8];
        #pragma unroll
        for (int mi = 0; mi < 4; ++mi)
            #pragma unroll
            for (int ni = 0; ni < 4; ++ni)
                acc[mi][ni] = __builtin_amdgcn_mfma_f32_16x16x32_bf16(
                    af[mi], bfv[ni], acc[mi][ni], 0, 0, 0);
        if (t < 7) {
            asm volatile("s_waitcnt vmcnt(0)" ::: "memory");
            __builtin_amdgcn_s_barrier();
        }
    }

    // Assemble [j][o] bf16 tile in LDS (stride 136)
    __syncthreads();
    u16* outl = sm;
    #pragma unroll
    for (int mi = 0; mi < 4; ++mi)
        #pragma unroll
        for (int ni = 0; ni < 4; ++ni) {
            const int jl = wn * 64 + ni * 16 + ln;
            const int ob = wm * 64 + mi * 16 + quad * 4;
            u16x4 u;
            u[0] = f2bf(acc[mi][ni][0]); u[1] = f2bf(acc[mi][ni][1]);
            u[2] = f2bf(acc[mi][ni][2]); u[3] = f2bf(acc[mi][ni][3]);
            *(u16x4*)&outl[jl * 136 + ob] = u;
        }
    __syncthreads();

    if (o0 < 256) {
        // q tiles: softmax over each 32-col head group, * 1/sqrt(32)
        #pragma unroll
        for (int t = 0; t < 2; ++t) {
            const int idx = t * 256 + tid;
            const int r = idx >> 2, hh = idx & 3;
            const u16* p = &outl[r * 136 + hh * 32];
            float v[32];
            float m = -1e30f;
            #pragma unroll
            for (int g = 0; g < 4; ++g) {
                u16x8 u = *(const u16x8*)(p + g * 8);
                #pragma unroll
                for (int i = 0; i < 8; ++i) {
                    v[g * 8 + i] = bf2f(u[i]);
                    m = fmaxf(m, v[g * 8 + i]);
                }
            }
            float s = 0.f;
            #pragma unroll
            for (int i = 0; i < 32; ++i) { v[i] = __expf(v[i] - m); s += v[i]; }
            const float inv = 0.17677669529663687f / s;
            u16* q = qkv + (size_t)(j0 + r) * 768 + o0 + hh * 32;
            #pragma unroll
            for (int g = 0; g < 4; ++g) {
                u16x8 ov;
                #pragma unroll
                for (int i = 0; i < 8; ++i) ov[i] = f2bf(v[g * 8 + i] * inv);
                *(u16x8*)(q + g * 8) = ov;
            }
        }
    } else {
        #pragma unroll
        for (int r = 0; r < 8; ++r) {
            const int row = r * 16 + (tid >> 4);
            const int cb = (tid & 15) * 8;
            u32x4 v = *(const u32x4*)&outl[row * 136 + cb];
            *(u32x4*)(qkv + (size_t)(j0 + row) * 768 + o0 + cb) = v;
        }
    }
}

// ---------------- S1: online (m,s) partials per k-col, per (fl, j-split) ----
__global__ __launch_bounds__(256) void k_kstat1(const u16* __restrict__ qkv,
                                                float* __restrict__ sp)
{
    const int js = blockIdx.x, fl = blockIdx.y;
    const int tid = threadIdx.x;
    const int s = tid >> 5, g = tid & 31;
    const u16* base = qkv + ((size_t)fl * 4096 + js * 256 + s) * 768 + 256 + g * 8;
    float m[8], sm[8];
    #pragma unroll
    for (int i = 0; i < 8; ++i) { m[i] = -1e30f; sm[i] = 0.f; }
    for (int it = 0; it < 32; ++it) {
        u16x8 u = *(const u16x8*)(base + (size_t)it * 8 * 768);
        #pragma unroll
        for (int i = 0; i < 8; ++i) {
            float v = bf2f(u[i]);
            float nm = fmaxf(m[i], v);
            sm[i] = sm[i] * __expf(m[i] - nm) + __expf(v - nm);
            m[i] = nm;
        }
    }
    __shared__ float Lm[8][256], Ls[8][256];
    #pragma unroll
    for (int i = 0; i < 8; ++i) { Lm[s][g * 8 + i] = m[i]; Ls[s][g * 8 + i] = sm[i]; }
    __syncthreads();
    const int col = tid;
    float M = -1e30f;
    #pragma unroll
    for (int k = 0; k < 8; ++k) M = fmaxf(M, Lm[k][col]);
    float S = 0.f;
    #pragma unroll
    for (int k = 0; k < 8; ++k) S += Ls[k][col] * __expf(Lm[k][col] - M);
    float* o = sp + (((size_t)fl * 16 + js) * 256 + col) * 2;
    o[0] = M; o[1] = S;
}

// ---------------- S2: combine 16 partials -> (M, 1/S) -----------------------
__global__ __launch_bounds__(256) void k_kstat2(const float* __restrict__ sp,
                                                float* __restrict__ stat)
{
    const int fl = blockIdx.x, col = threadIdx.x;
    float mv[16], sv[16];
    float M = -1e30f;
    #pragma unroll
    for (int js = 0; js < 16; ++js) {
        const float* p = sp + (((size_t)fl * 16 + js) * 256 + col) * 2;
        mv[js] = p[0]; sv[js] = p[1];
        M = fmaxf(M, mv[js]);
    }
    float S = 0.f;
    #pragma unroll
    for (int js = 0; js < 16; ++js) S += sv[js] * __expf(mv[js] - M);
    float* o = stat + ((size_t)fl * 256 + col) * 2;
    o[0] = M; o[1] = 1.0f / S;
}

// ---------------- CX: P[h][d][e] += exp(k-M)*v, per (fl, j-split) -----------
__global__ __launch_bounds__(256) void k_ctx(const u16* __restrict__ qkv,
                                             const float* __restrict__ stat,
                                             float* __restrict__ P)
{
    const int js = blockIdx.x, fl = blockIdx.y;
    const int tid = threadIdx.x;
    const int ls = tid >> 5, lg = tid & 31;                  // staging role
    const int h = tid >> 5, dg = (tid >> 3) & 3, eg = tid & 7;  // acc role
    const int d0 = dg * 8, e0 = eg * 4;

    float Mg[8];
    #pragma unroll
    for (int i = 0; i < 8; ++i) Mg[i] = stat[((size_t)fl * 256 + lg * 8 + i) * 2];

    __shared__ float expk[8][264], vbuf[8][264];
    f32x4 acc[8] = {};
    const u16* kbase = qkv + ((size_t)fl * 4096 + js * 256 + ls) * 768 + 256 + lg * 8;

    for (int ch = 0; ch < 32; ++ch) {
        const u16* kp = kbase + (size_t)ch * 8 * 768;
        u16x8 ku = *(const u16x8*)kp;
        u16x8 vu = *(const u16x8*)(kp + 256);
        __syncthreads();
        #pragma unroll
        for (int i = 0; i < 8; ++i) {
            expk[ls][lg * 8 + i] = __expf(bf2f(ku[i]) - Mg[i]);
            vbuf[ls][lg * 8 + i] = bf2f(vu[i]);
        }
        __syncthreads();
        #pragma unroll
        for (int rr = 0; rr < 8; ++rr) {
            f32x4 w0 = *(const f32x4*)&expk[rr][h * 32 + d0];
            f32x4 w1 = *(const f32x4*)&expk[rr][h * 32 + d0 + 4];
            f32x4 vv = *(const f32x4*)&vbuf[rr][h * 32 + e0];
            #pragma unroll
            for (int ei = 0; ei < 4; ++ei) {
                acc[0][ei] = fmaf(w0[0], vv[ei], acc[0][ei]);
                acc[1][ei] = fmaf(w0[1], vv[ei], acc[1][ei]);
                acc[2][ei] = fmaf(w0[2], vv[ei], acc[2][ei]);
                acc[3][ei] = fmaf(w0[3], vv[ei], acc[3][ei]);
                acc[4][ei] = fmaf(w1[0], vv[ei], acc[4][ei]);
                acc[5][ei] = fmaf(w1[1], vv[ei], acc[5][ei]);
                acc[6][ei] = fmaf(w1[2], vv[ei], acc[6][ei]);
                acc[7][ei] = fmaf(w1[3], vv[ei], acc[7][ei]);
            }
        }
    }
    float* o = P + ((size_t)fl * 16 + js) * 8192 + (h * 32 + d0) * 32 + e0;
    #pragma unroll
    for (int di = 0; di < 8; ++di) *(f32x4*)(o + di * 32) = acc[di];
}

// ---------------- W2: sum partials, *invS, fold w_out -> W2 bf16 ------------
__global__ __launch_bounds__(256) void k_w2fold(const float* __restrict__ P,
                                                const float* __restrict__ stat,
                                                const float* __restrict__ w_out,
                                                u16* __restrict__ w2)
{
    const int h = blockIdx.x, fl = blockIdx.y;
    const int tid = threadIdx.x;
    __shared__ float Cs[32 * 33];

    const float* p0 = P + (size_t)fl * 16 * 8192 + h * 1024 + tid * 4;
    f32x4 sum = {0.f, 0.f, 0.f, 0.f};
    #pragma unroll
    for (int js = 0; js < 16; ++js) {
        f32x4 v = *(const f32x4*)(p0 + (size_t)js * 8192);
        sum[0] += v[0]; sum[1] += v[1]; sum[2] += v[2]; sum[3] += v[3];
    }
    const int d = tid >> 3, e4 = (tid & 7) * 4;
    const float inv = stat[((size_t)fl * 256 + h * 32 + d) * 2 + 1];
    Cs[d * 33 + e4 + 0] = sum[0] * inv;
    Cs[d * 33 + e4 + 1] = sum[1] * inv;
    Cs[d * 33 + e4 + 2] = sum[2] * inv;
    Cs[d * 33 + e4 + 3] = sum[3] * inv;
    __syncthreads();

    const int o = tid;
    float a2[32];
    #pragma unroll
    for (int dd = 0; dd < 32; ++dd) a2[dd] = 0.f;
    for (int e = 0; e < 32; ++e) {
        const float wv = w_out[(size_t)o * 256 + h * 32 + e];
        #pragma unroll
        for (int dd = 0; dd < 32; ++dd) a2[dd] = fmaf(wv, Cs[dd * 33 + e], a2[dd]);
    }
    u16* wp = w2 + (size_t)fl * 65536 + (size_t)o * 256 + h * 32;
    #pragma unroll
    for (int g = 0; g < 4; ++g) {
        u16x8 ov;
        #pragma unroll
        for (int i = 0; i < 8; ++i) ov[i] = f2bf(a2[g * 8 + i]);
        *(u16x8*)(wp + g * 8) = ov;
    }
}

// ---------------- K5: out = MFMA(q, W2) + b_out, fp32 direct store ----------
// grid: 1-D, CF*32*2 blocks; XCD-chunked swizzle, o fastest within XCD
__global__ __launch_bounds__(256) void k_out_mfma(const u16* __restrict__ qkv,
                                                  const u16* __restrict__ w2,
                                                  const float* __restrict__ b_out,
                                                  float* __restrict__ out, int fr0)
{
    const int tid = threadIdx.x;
    const int lane = tid & 63, wave = tid >> 6;
    const int ln = lane & 15, quad = lane >> 4;
    const int wm = wave & 1, wn = wave >> 1;

    const int chunk = gridDim.x >> 3;
    const int newid = (blockIdx.x & 7) * chunk + (blockIdx.x >> 3);
    const int o0 = (newid & 1) * 128;   // N tile (W2 rows) — fastest
    const int j0 = (newid >> 1) * 128;  // M tile (q rows, local j)

    const int fl = j0 >> 12;
    const int frame = fr0 + fl, b = frame >> 4, f = frame & 15;
    const int nb = j0 & 4095;
    const u16* w2f = w2 + (size_t)fl * 65536;

    __shared__ __align__(16) u16 sm[16384];   // 2 x (As 4096 + Bs 4096)

    f32x4 acc[4][4] = {};
    const int lrow = lane >> 2;
    const int lk8 = ((lane & 3) ^ ((lrow >> 1) & 3)) * 8;   // pre-swizzled src
    const int sw8 = (quad ^ ((ln >> 1) & 3)) * 8;           // swizzled ds_read

    const u16* gA = qkv + (size_t)j0 * 768;
    const u16* gB = w2f + (size_t)o0 * 256;
    const int r0 = wave * 32 + lrow;

    // prologue: stage K-step 0 into buf 0
    {
        u16* A = sm;      u16* B = sm + 4096;
        async16(gA + (size_t)r0 * 768 + lk8,          A + (wave*2) * 512);
        async16(gB + (size_t)r0 * 256 + lk8,          B + (wave*2) * 512);
        async16(gA + (size_t)(r0+16) * 768 + lk8,     A + (wave*2+1) * 512);
        async16(gB + (size_t)(r0+16) * 256 + lk8,     B + (wave*2+1) * 512);
    }
    asm volatile("s_waitcnt vmcnt(0)" ::: "memory");
    __builtin_amdgcn_s_barrier();

    #pragma unroll
    for (int t = 0; t < 8; ++t) {
        const int cur = t & 1;
        if (t < 7) {
            u16* A = sm + (cur ^ 1) * 8192;
            u16* B = A + 4096;
            const int kk = (t + 1) * 32;
            async16(gA + (size_t)r0 * 768 + kk + lk8,      A + (wave*2) * 512);
            async16(gB + (size_t)r0 * 256 + kk + lk8,      B + (wave*2) * 512);
            async16(gA + (size_t)(r0+16) * 768 + kk + lk8, A + (wave*2+1) * 512);
            async16(gB + (size_t)(r0+16) * 256 + kk + lk8, B + (wave*2+1) * 512);
        }
        const u16* As = sm + cur * 8192;
        const u16* Bs = As + 4096;
        bf16x8 af[4], bfv[4];
        #pragma unroll
        for (int mi = 0; mi < 4; ++mi)
            af[mi] = *(const bf16x8*)&As[(wm * 64 + mi * 16 + ln) * 32 + sw8];
        #pragma unroll
        for (int ni = 0; ni < 4; ++ni)
            bfv[ni] = *(const bf16x8*)&Bs[(wn * 64 + ni * 16 + ln) * 32 + sw8];
        #pragma unroll
        for (int mi = 0; mi < 4; ++mi)
            #pragma unroll
            for (int ni = 0; ni < 4; ++ni)
                acc[mi][ni] = __builtin_amdgcn_mfma_f32_16x16x32_bf16(
                    af[mi], bfv[ni], acc[mi][ni], 0, 0, 0);
        if (t < 7) {
            asm volatile("s_waitcnt vmcnt(0)" ::: "memory");
            __builtin_amdgcn_s_barrier();
        }
    }

    float* obase = out + (size_t)b * XB_STRIDE + (size_t)f * 4096;
    #pragma unroll
    for (int ni = 0; ni < 4; ++ni) {
        const int o = o0 + wn * 64 + ni * 16 + ln;
        const float bias = b_out[o];
        #pragma unroll
        for (int mi = 0; mi < 4; ++mi) {
            const int jn = nb + wm * 64 + mi * 16 + quad * 4;
            f32x4 v = acc[mi][ni];
            v[0] += bias; v[1] += bias; v[2] += bias; v[3] += bias;
            *(f32x4*)(obase + (size_t)o * XCH_STRIDE + jn) = v;
        }
    }
}

// ---------------------------------------------------------------------------
extern "C" void kernel_launch(void* const* d_in, const int* in_sizes, int n_in,
                              void* d_out, int out_size, void* d_ws, size_t ws_size,
                              hipStream_t stream)
{
    const float* x     = (const float*)d_in[0];
    const float* w_qkv = (const float*)d_in[1];
    const float* w_out = (const float*)d_in[2];
    const float* b_out = (const float*)d_in[3];
    float* out = (float*)d_out;

    // ws per frame: xbf 2MB + qkv 6MB + w2 128KB + sp 32KB + stat 2KB + P 512KB
    const size_t per_frame = (size_t)4096 * 256 * 2 + (size_t)4096 * 768 * 2
                           + 65536 * 2 + 16 * 512 * 4 + 512 * 4 + 16 * 8192 * 4;
    const size_t wq_bytes = 768 * 256 * 2;
    int CF = 32;
    while (CF > 1 && (size_t)CF * per_frame + wq_bytes > ws_size) CF >>= 1;

    u16* wq_bf  = (u16*)d_ws;
    u16* xbf    = wq_bf + 768 * 256;
    u16* qkv    = xbf + (size_t)CF * 4096 * 256;
    u16* w2     = qkv + (size_t)CF * 4096 * 768;
    float* sp   = (float*)(w2 + (size_t)CF * 65536);
    float* stat = sp + (size_t)CF * 16 * 256 * 2;
    float* P    = stat + (size_t)CF * 256 * 2;

    k_cvt_w<<<96, 256, 0, stream>>>(w_qkv, wq_bf);
    for (int fr0 = 0; fr0 < 32; fr0 += CF) {
        k_cvt_x   <<<dim3(64, 4, CF), 256, 0, stream>>>(x, xbf, fr0);
        k_qkv_mfma<<<CF * 32 * 6, 256, 0, stream>>>(xbf, wq_bf, qkv);
        k_kstat1  <<<dim3(16, CF), 256, 0, stream>>>(qkv, sp);
        k_kstat2  <<<CF, 256, 0, stream>>>(sp, stat);
        k_ctx     <<<dim3(16, CF), 256, 0, stream>>>(qkv, stat, P);
        k_w2fold  <<<dim3(8, CF), 256, 0, stream>>>(P, stat, w_out, w2);
        k_out_mfma<<<CF * 32 * 2, 256, 0, stream>>>(qkv, w2, b_out, out, fr0);
    }
}